// Round 6
// baseline (261.278 us; speedup 1.0000x reference)
//
#include <hip/hip_runtime.h>

#define CC 32
#define HH 256
#define WW 512
#define DD 64
#define WB 256              // w-width per block (row split in 2)
#define PRE 64              // r prefix words (covers d<=63 reach-back)
#define RT (WB + PRE)       // 320 words per r row in LDS
#define CHUNK 16            // channels per LDS pass
#define NCHUNK (CC / CHUNK) // 2

__global__ __launch_bounds__(256, 4) void cost_volume_kernel(
    const float* __restrict__ L, const float* __restrict__ R, float* __restrict__ O)
{
    // 16 KiB l + 20 KiB r = 36 KiB -> 4 blocks/CU (VGPR-capped at 16 waves)
    __shared__ float lA[CHUNK * WB];
    __shared__ float rB[CHUNK * RT];

    const int tid = threadIdx.x;
    const int bid = blockIdx.x;
    const int half = bid & 1;
    const int row = bid >> 1;           // n*H + h
    const int n = row >> 8;
    const int h = row & 255;
    const int wstart = half * WB;
    const size_t inbase = (size_t)n * (CC * HH * WW) + (size_t)h * WW + wstart;

    // half 0: zero the 64-word prefix of each r row ONCE (in-loop staging
    // never touches words [0,PRE) when half==0, so zeros persist).
    if (half == 0) {
        const int c = tid >> 4, q = tid & 15;   // 16 rows x 16 float4
        *reinterpret_cast<float4*>(&rB[c * RT + q * 4]) =
            make_float4(0.f, 0.f, 0.f, 0.f);
    }

    // thread -> (d-tile, w-chunk): 4 waves x 64 lanes = 4 d-tiles x 64 w-tiles
    const int wave = tid >> 6, lane = tid & 63;
    const int d0 = wave * 16;
    const int w0 = lane * 4;                    // local w in [0,256)
    const int rbase = PRE + w0 - d0 - 16;       // in [0,300]; +20 words <= 320

    float acc[16][4];
    #pragma unroll
    for (int dd = 0; dd < 16; ++dd)
        #pragma unroll
        for (int j = 0; j < 4; ++j) acc[dd][j] = 0.f;

    // T14 reg-prefetch (same proven schedule as R5): global->reg early,
    // reg->LDS late. All prefetch regs individually named (static indexing).
    float4 lr0, lr1, lr2, lr3, rr0, rr1, rr2, rr3, pr;
    const int c_0 = (tid          ) >> 6, q_0 = (tid          ) & 63;
    const int c_1 = (tid + 256    ) >> 6, q_1 = (tid + 256    ) & 63;
    const int c_2 = (tid + 512    ) >> 6, q_2 = (tid + 512    ) & 63;
    const int c_3 = (tid + 768    ) >> 6, q_3 = (tid + 768    ) & 63;
    const int cp  = tid >> 4,             qp  = tid & 15;       // prefix map

    auto ld = [&](int ch) {
        const int c0 = ch * CHUNK;
        const size_t g0 = inbase + (size_t)(c0 + c_0) * (HH * WW);
        const size_t g1 = inbase + (size_t)(c0 + c_1) * (HH * WW);
        const size_t g2 = inbase + (size_t)(c0 + c_2) * (HH * WW);
        const size_t g3 = inbase + (size_t)(c0 + c_3) * (HH * WW);
        lr0 = reinterpret_cast<const float4*>(L + g0)[q_0];
        rr0 = reinterpret_cast<const float4*>(R + g0)[q_0];
        lr1 = reinterpret_cast<const float4*>(L + g1)[q_1];
        rr1 = reinterpret_cast<const float4*>(R + g1)[q_1];
        lr2 = reinterpret_cast<const float4*>(L + g2)[q_2];
        rr2 = reinterpret_cast<const float4*>(R + g2)[q_2];
        lr3 = reinterpret_cast<const float4*>(L + g3)[q_3];
        rr3 = reinterpret_cast<const float4*>(R + g3)[q_3];
        if (half == 1) {   // real data for words [wstart-64, wstart)
            const size_t gp = inbase + (size_t)(c0 + cp) * (HH * WW) - PRE;
            pr = reinterpret_cast<const float4*>(R + gp)[qp];
        }
    };
    auto wr = [&]() {
        *reinterpret_cast<float4*>(&lA[c_0 * WB + q_0 * 4]) = lr0;
        *reinterpret_cast<float4*>(&rB[c_0 * RT + PRE + q_0 * 4]) = rr0;
        *reinterpret_cast<float4*>(&lA[c_1 * WB + q_1 * 4]) = lr1;
        *reinterpret_cast<float4*>(&rB[c_1 * RT + PRE + q_1 * 4]) = rr1;
        *reinterpret_cast<float4*>(&lA[c_2 * WB + q_2 * 4]) = lr2;
        *reinterpret_cast<float4*>(&rB[c_2 * RT + PRE + q_2 * 4]) = rr2;
        *reinterpret_cast<float4*>(&lA[c_3 * WB + q_3 * 4]) = lr3;
        *reinterpret_cast<float4*>(&rB[c_3 * RT + PRE + q_3 * 4]) = rr3;
        if (half == 1)
            *reinterpret_cast<float4*>(&rB[cp * RT + qp * 4]) = pr;
    };

    ld(0);   // chunk-0 loads fly during prefix-zeroing / launch

    for (int ch = 0; ch < NCHUNK; ++ch) {
        __syncthreads();   // compute(ch-1) done -> LDS writable (pads visible at ch=0)

        wr();                              // vmcnt wait lands here, long after issue
        if (ch + 1 < NCHUNK) ld(ch + 1);   // next chunk's loads issued NOW

        __syncthreads();   // stage(ch) visible

        #pragma unroll 4
        for (int c = 0; c < CHUNK; ++c) {
            const float4 lv = *reinterpret_cast<const float4*>(&lA[c * WB + w0]);
            float rwin[20];
            #pragma unroll
            for (int k = 0; k < 5; ++k) {
                const float4 rv = *reinterpret_cast<const float4*>(&rB[c * RT + rbase + k * 4]);
                rwin[k * 4 + 0] = rv.x; rwin[k * 4 + 1] = rv.y;
                rwin[k * 4 + 2] = rv.z; rwin[k * 4 + 3] = rv.w;
            }
            const float lvv[4] = {lv.x, lv.y, lv.z, lv.w};
            #pragma unroll
            for (int dd = 0; dd < 16; ++dd)
                #pragma unroll
                for (int j = 0; j < 4; ++j)
                    acc[dd][j] = fmaf(lvv[j], rwin[16 + j - dd], acc[dd][j]);
        }
    }

    const float inv = 1.0f / 32.0f;
    const size_t obase = (size_t)n * ((size_t)DD * HH * WW) + (size_t)h * WW
                       + wstart + w0;
    #pragma unroll
    for (int dd = 0; dd < 16; ++dd) {
        float4 o;
        o.x = acc[dd][0] * inv; o.y = acc[dd][1] * inv;
        o.z = acc[dd][2] * inv; o.w = acc[dd][3] * inv;
        *reinterpret_cast<float4*>(&O[obase + (size_t)(d0 + dd) * (HH * WW)]) = o;
    }
}

extern "C" void kernel_launch(void* const* d_in, const int* in_sizes, int n_in,
                              void* d_out, int out_size, void* d_ws, size_t ws_size,
                              hipStream_t stream) {
    const float* L = (const float*)d_in[0];
    const float* R = (const float*)d_in[1];
    float* O = (float*)d_out;
    cost_volume_kernel<<<8 * HH * 2, 256, 0, stream>>>(L, R, O);
}

// Round 7
// 206.095 us; speedup vs baseline: 1.2678x; 1.2678x over previous
//
#include <hip/hip_runtime.h>

#define CC 32
#define HH 256
#define WW 512
#define DD 64
#define PAD 64
#define RPITCH (WW + PAD)   // 576 words per padded r row in LDS
#define CHUNK 4             // channels per LDS pass (keeps prefetch at 16 VGPRs)
#define NCHUNK (CC / CHUNK) // 8

__global__ __launch_bounds__(256) void cost_volume_kernel(
    const float* __restrict__ L, const float* __restrict__ R, float* __restrict__ O)
{
    // 4 ch x (512 l + 576 r) x 4B = 17 KiB LDS; occupancy VGPR-capped (~2 blocks/CU)
    __shared__ float lA[CHUNK * WW];
    __shared__ float rB[CHUNK * RPITCH];

    const int tid = threadIdx.x;
    const int row = blockIdx.x;          // n*H + h
    const int n = row >> 8;
    const int h = row & 255;
    const size_t inbase = (size_t)n * (CC * HH * WW) + (size_t)h * WW;

    // zero the 64-word left pad of each r row once; staging never touches
    // words [0,PAD) of a row, so pads stay zero across all chunks.
    if (tid < CHUNK * 16) {
        const int c = tid >> 4, q = tid & 15;
        *reinterpret_cast<float4*>(&rB[c * RPITCH + q * 4]) =
            make_float4(0.f, 0.f, 0.f, 0.f);
    }

    // thread tile: 16 disparities x 8 widths. 4 waves x 64 lanes cover 64d x 512w.
    const int wave = tid >> 6, lane = tid & 63;
    const int d0 = wave * 16;
    const int w0 = lane * 8;
    const int rbase = PAD + w0 - d0 - 16;   // in [0,552]; +24 words <= 576

    float acc[16][8];
    #pragma unroll
    for (int dd = 0; dd < 16; ++dd)
        #pragma unroll
        for (int j = 0; j < 8; ++j) acc[dd][j] = 0.f;

    // T14 reg-prefetch, same proven R5 schedule. 4 float4 prefetch regs only.
    float4 lr0, lr1, rr0, rr1;
    const int c_0 = (tid      ) >> 7, q_0 = (tid      ) & 127;
    const int c_1 = (tid + 256) >> 7, q_1 = (tid + 256) & 127;

    auto ld = [&](int ch) {
        const int c0 = ch * CHUNK;
        const size_t g0 = inbase + (size_t)(c0 + c_0) * (HH * WW);
        const size_t g1 = inbase + (size_t)(c0 + c_1) * (HH * WW);
        lr0 = reinterpret_cast<const float4*>(L + g0)[q_0];
        rr0 = reinterpret_cast<const float4*>(R + g0)[q_0];
        lr1 = reinterpret_cast<const float4*>(L + g1)[q_1];
        rr1 = reinterpret_cast<const float4*>(R + g1)[q_1];
    };

    ld(0);   // chunk-0 loads fly during pad-zeroing / launch

    for (int ch = 0; ch < NCHUNK; ++ch) {
        __syncthreads();   // compute(ch-1) done -> LDS writable (pads visible at ch=0)

        // reg -> LDS (vmcnt wait lands here, one compute phase after issue)
        *reinterpret_cast<float4*>(&lA[c_0 * WW + q_0 * 4]) = lr0;
        *reinterpret_cast<float4*>(&rB[c_0 * RPITCH + PAD + q_0 * 4]) = rr0;
        *reinterpret_cast<float4*>(&lA[c_1 * WW + q_1 * 4]) = lr1;
        *reinterpret_cast<float4*>(&rB[c_1 * RPITCH + PAD + q_1 * 4]) = rr1;

        if (ch + 1 < NCHUNK) ld(ch + 1);   // issue next chunk's loads NOW

        __syncthreads();   // stage(ch) visible

        #pragma unroll
        for (int c = 0; c < CHUNK; ++c) {
            const float4 la = *reinterpret_cast<const float4*>(&lA[c * WW + w0]);
            const float4 lb = *reinterpret_cast<const float4*>(&lA[c * WW + w0 + 4]);
            float rwin[24];
            #pragma unroll
            for (int k = 0; k < 6; ++k) {
                const float4 rv = *reinterpret_cast<const float4*>(&rB[c * RPITCH + rbase + k * 4]);
                rwin[k * 4 + 0] = rv.x; rwin[k * 4 + 1] = rv.y;
                rwin[k * 4 + 2] = rv.z; rwin[k * 4 + 3] = rv.w;
            }
            const float lvv[8] = {la.x, la.y, la.z, la.w, lb.x, lb.y, lb.z, lb.w};
            #pragma unroll
            for (int dd = 0; dd < 16; ++dd)
                #pragma unroll
                for (int j = 0; j < 8; ++j)
                    acc[dd][j] = fmaf(lvv[j], rwin[16 + j - dd], acc[dd][j]);
        }
    }

    const float inv = 1.0f / 32.0f;
    const size_t obase = (size_t)n * ((size_t)DD * HH * WW) + (size_t)h * WW + w0;
    #pragma unroll
    for (int dd = 0; dd < 16; ++dd) {
        const size_t ob = obase + (size_t)(d0 + dd) * (HH * WW);
        float4 o1, o2;
        o1.x = acc[dd][0] * inv; o1.y = acc[dd][1] * inv;
        o1.z = acc[dd][2] * inv; o1.w = acc[dd][3] * inv;
        o2.x = acc[dd][4] * inv; o2.y = acc[dd][5] * inv;
        o2.z = acc[dd][6] * inv; o2.w = acc[dd][7] * inv;
        *reinterpret_cast<float4*>(&O[ob]) = o1;
        *reinterpret_cast<float4*>(&O[ob + 4]) = o2;
    }
}

extern "C" void kernel_launch(void* const* d_in, const int* in_sizes, int n_in,
                              void* d_out, int out_size, void* d_ws, size_t ws_size,
                              hipStream_t stream) {
    const float* L = (const float*)d_in[0];
    const float* R = (const float*)d_in[1];
    float* O = (float*)d_out;
    cost_volume_kernel<<<8 * HH, 256, 0, stream>>>(L, R, O);
}

// Round 8
// 124.049 us; speedup vs baseline: 2.1062x; 1.6614x over previous
//
#include <hip/hip_runtime.h>

#define CC 32
#define HH 256
#define WW 512
#define DD 64
#define PAD 64
#define RPITCH (WW + PAD)   // 576 words per padded r row (576%64==0: swizzle-safe)
#define CHUNK 4             // channels per LDS pass
#define NCHUNK (CC / CHUNK) // 8

// bank-balance swizzle: fold word-bit5 into float4-slot bit2.
// involution; constant over any 4-aligned float4 group -> b128 stays b128.
__device__ __forceinline__ int swz(int y) { return y ^ (((y >> 5) & 1) << 2); }

__global__ __launch_bounds__(256) void cost_volume_kernel(
    const float* __restrict__ L, const float* __restrict__ R, float* __restrict__ O)
{
    __shared__ float lA[CHUNK * WW];     // 8 KiB
    __shared__ float rB[CHUNK * RPITCH]; // 9 KiB

    const int tid = threadIdx.x;
    const int row = blockIdx.x;          // n*H + h
    const int n = row >> 8;
    const int h = row & 255;
    const size_t inbase = (size_t)n * (CC * HH * WW) + (size_t)h * WW;

    // zero the 64-word left pad of each r row once (swizzled addresses).
    if (tid < CHUNK * 16) {
        const int c = tid >> 4, q = tid & 15;
        *reinterpret_cast<float4*>(&rB[c * RPITCH + swz(q * 4)]) =
            make_float4(0.f, 0.f, 0.f, 0.f);
    }

    // thread tile: 16 disparities x 8 widths. 4 waves x 64 lanes = 64d x 512w.
    const int wave = tid >> 6, lane = tid & 63;
    const int d0 = wave * 16;
    const int w0 = lane * 8;
    const int rbase = PAD + w0 - d0 - 16;   // 4-aligned, in [0,552]

    // precomputed swizzled read offsets (thread-constant; c-term is bit6+ only)
    const int loffA = swz(w0);
    const int loffB = swz(w0 + 4);
    int roff[6];
    #pragma unroll
    for (int k = 0; k < 6; ++k) roff[k] = swz(rbase + 4 * k);

    float acc[16][8];
    #pragma unroll
    for (int dd = 0; dd < 16; ++dd)
        #pragma unroll
        for (int j = 0; j < 8; ++j) acc[dd][j] = 0.f;

    // T14 reg-prefetch (proven R5/R7 schedule). Swizzled LDS write offsets.
    float4 lr0, lr1, rr0, rr1;
    const int c_0 = (tid      ) >> 7, q_0 = (tid      ) & 127;
    const int c_1 = (tid + 256) >> 7, q_1 = (tid + 256) & 127;
    const int wl0 = swz(q_0 * 4),       wl1 = swz(q_1 * 4);
    const int wr0 = swz(PAD + q_0 * 4), wr1 = swz(PAD + q_1 * 4);

    auto ld = [&](int ch) {
        const int c0 = ch * CHUNK;
        const size_t g0 = inbase + (size_t)(c0 + c_0) * (HH * WW);
        const size_t g1 = inbase + (size_t)(c0 + c_1) * (HH * WW);
        lr0 = reinterpret_cast<const float4*>(L + g0)[q_0];
        rr0 = reinterpret_cast<const float4*>(R + g0)[q_0];
        lr1 = reinterpret_cast<const float4*>(L + g1)[q_1];
        rr1 = reinterpret_cast<const float4*>(R + g1)[q_1];
    };

    ld(0);

    for (int ch = 0; ch < NCHUNK; ++ch) {
        __syncthreads();   // compute(ch-1) done -> LDS writable (pads visible at ch=0)

        *reinterpret_cast<float4*>(&lA[c_0 * WW + wl0]) = lr0;
        *reinterpret_cast<float4*>(&rB[c_0 * RPITCH + wr0]) = rr0;
        *reinterpret_cast<float4*>(&lA[c_1 * WW + wl1]) = lr1;
        *reinterpret_cast<float4*>(&rB[c_1 * RPITCH + wr1]) = rr1;

        if (ch + 1 < NCHUNK) ld(ch + 1);   // next chunk's loads fly during compute

        __syncthreads();   // stage(ch) visible

        #pragma unroll
        for (int c = 0; c < CHUNK; ++c) {
            const float4 la = *reinterpret_cast<const float4*>(&lA[c * WW + loffA]);
            const float4 lb = *reinterpret_cast<const float4*>(&lA[c * WW + loffB]);
            float rwin[24];
            #pragma unroll
            for (int k = 0; k < 6; ++k) {
                const float4 rv = *reinterpret_cast<const float4*>(&rB[c * RPITCH + roff[k]]);
                rwin[k * 4 + 0] = rv.x; rwin[k * 4 + 1] = rv.y;
                rwin[k * 4 + 2] = rv.z; rwin[k * 4 + 3] = rv.w;
            }
            const float lvv[8] = {la.x, la.y, la.z, la.w, lb.x, lb.y, lb.z, lb.w};
            #pragma unroll
            for (int dd = 0; dd < 16; ++dd)
                #pragma unroll
                for (int j = 0; j < 8; ++j)
                    acc[dd][j] = fmaf(lvv[j], rwin[16 + j - dd], acc[dd][j]);
        }
    }

    const float inv = 1.0f / 32.0f;
    const size_t obase = (size_t)n * ((size_t)DD * HH * WW) + (size_t)h * WW + w0;
    #pragma unroll
    for (int dd = 0; dd < 16; ++dd) {
        const size_t ob = obase + (size_t)(d0 + dd) * (HH * WW);
        float4 o1, o2;
        o1.x = acc[dd][0] * inv; o1.y = acc[dd][1] * inv;
        o1.z = acc[dd][2] * inv; o1.w = acc[dd][3] * inv;
        o2.x = acc[dd][4] * inv; o2.y = acc[dd][5] * inv;
        o2.z = acc[dd][6] * inv; o2.w = acc[dd][7] * inv;
        *reinterpret_cast<float4*>(&O[ob]) = o1;
        *reinterpret_cast<float4*>(&O[ob + 4]) = o2;
    }
}

extern "C" void kernel_launch(void* const* d_in, const int* in_sizes, int n_in,
                              void* d_out, int out_size, void* d_ws, size_t ws_size,
                              hipStream_t stream) {
    const float* L = (const float*)d_in[0];
    const float* R = (const float*)d_in[1];
    float* O = (float*)d_out;
    cost_volume_kernel<<<8 * HH, 256, 0, stream>>>(L, R, O);
}